// Round 6
// baseline (157.398 us; speedup 1.0000x reference)
//
#include <hip/hip_runtime.h>
#include <hip/hip_cooperative_groups.h>
#include <hip/hip_bf16.h>
#include <math.h>

namespace cg = cooperative_groups;

// B=16, S=T=512, D=512, R=8.  All float32.
#define B 16
#define Sn 512
#define Tn 512
#define Dn 512
#define Rn 8
#define NEG_BIG (-1e10f)
#define L2E 1.4426950408889634f

#define NBLK 512  // 2 blocks/CU on 256 CUs -> always co-resident

__device__ __forceinline__ float dot4(float4 a, float4 b) {
  return a.x * b.x + a.y * b.y + a.z * b.z + a.w * b.w;
}

// Sum p[0..7] across 64 lanes with 10 shuffles. Every lane returns the
// total for r = lane&7.
__device__ __forceinline__ float fold_reduce8(const float* p, int lane) {
  bool b0 = lane & 1;
  float q[4];
#pragma unroll
  for (int j = 0; j < 4; ++j) {
    float s = b0 ? p[2 * j] : p[2 * j + 1];
    float rv = __shfl_xor(s, 1, 64);
    q[j] = (b0 ? p[2 * j + 1] : p[2 * j]) + rv;
  }
  bool b1 = lane & 2;
  float u[2];
#pragma unroll
  for (int j = 0; j < 2; ++j) {
    float s = b1 ? q[2 * j] : q[2 * j + 1];
    float rv = __shfl_xor(s, 2, 64);
    u[j] = (b1 ? q[2 * j + 1] : q[2 * j]) + rv;
  }
  bool b2 = lane & 4;
  float s = b2 ? u[0] : u[1];
  float rv = __shfl_xor(s, 4, 64);
  float v = (b2 ? u[1] : u[0]) + rv;
  v += __shfl_xor(v, 8, 64);
  v += __shfl_xor(v, 16, 64);
  v += __shfl_xor(v, 32, 64);
  return v;
}

// w[8][512] -> registers (lane's d4-slices: lane and 64+lane), row-normalized;
// g[r] = ||w_r||^2 post-normalize (kept for bit-faithfulness to reference).
__device__ __forceinline__ void load_norm_w(const float* __restrict__ w,
                                            int lane, float4* wa, float4* wb,
                                            float* g) {
  const float4* wg = (const float4*)w;
  float ss[8];
#pragma unroll
  for (int r = 0; r < 8; ++r) {
    wa[r] = wg[r * 128 + lane];
    wb[r] = wg[r * 128 + 64 + lane];
    ss[r] = dot4(wa[r], wa[r]) + dot4(wb[r], wb[r]);
  }
#pragma unroll
  for (int off = 32; off; off >>= 1) {
#pragma unroll
    for (int r = 0; r < 8; ++r) ss[r] += __shfl_xor(ss[r], off, 64);
  }
#pragma unroll
  for (int r = 0; r < 8; ++r) {
    float iv = 1.0f / fmaxf(sqrtf(ss[r]), 1e-12f);
    wa[r].x *= iv; wa[r].y *= iv; wa[r].z *= iv; wa[r].w *= iv;
    wb[r].x *= iv; wb[r].y *= iv; wb[r].z *= iv; wb[r].w *= iv;
    g[r] = ss[r] * iv * iv;
  }
}

// ---------------------------------------------------------------------------
// Phase 1: wt[row][r] = <emb[row,:], w_norm[r,:]>; 32 rows/block, 8/wave.
__device__ __forceinline__ void phase1(int blk, int tid,
                                       const float* __restrict__ src_emb,
                                       const float* __restrict__ tar_emb,
                                       const float4* wa, const float4* wb,
                                       float* __restrict__ src_wt,
                                       float* __restrict__ tar_wt) {
  int lane = tid & 63, wid = tid >> 6;
  int row0 = blk * 32 + wid * 8;
  bool is_src = row0 < B * Sn;
  const float* emb = is_src ? src_emb : tar_emb;
  float* wt = is_src ? src_wt : tar_wt;
  int rb = is_src ? row0 : row0 - B * Sn;

#pragma unroll
  for (int i = 0; i < 8; i += 2) {
    const float4* e0 = (const float4*)(emb + (size_t)(rb + i) * Dn);
    const float4* e1 = (const float4*)(emb + (size_t)(rb + i + 1) * Dn);
    float4 x0a = e0[lane], x0b = e0[64 + lane];
    float4 x1a = e1[lane], x1b = e1[64 + lane];
    float p0[8], p1[8];
#pragma unroll
    for (int r = 0; r < 8; ++r) {
      p0[r] = dot4(x0a, wa[r]) + dot4(x0b, wb[r]);
      p1[r] = dot4(x1a, wa[r]) + dot4(x1b, wb[r]);
    }
    float v0 = fold_reduce8(p0, lane);  // independent chains -> ILP
    float v1 = fold_reduce8(p1, lane);
    if (lane < 8) wt[(size_t)(rb + i) * 8 + lane] = v0;
    else if (lane < 16) wt[(size_t)(rb + i + 1) * 8 + (lane & 7)] = v1;
  }
}

// ---------------------------------------------------------------------------
// Phase 2: fused softmax + output for 16 s-rows per block.
// Lane owns (s_local&3 via lane>>4, r=lane&7, t-half=(lane>>3)&1); serial
// t-loop, zero shuffles inside; softmax via analytic bound (shift-invariant).
__device__ __forceinline__ void phase2(int blk, int tid,
                                       const float* __restrict__ src_wt,
                                       const float* __restrict__ tar_wt,
                                       const float* __restrict__ src_mask,
                                       const float* __restrict__ tar_mask,
                                       const float4* wa, const float4* wb,
                                       const float* g,
                                       float* __restrict__ out, float* tw_lds,
                                       float* tm_lds, float* cacc_lds,
                                       float* mred) {
  int lane = tid & 63, wid = tid >> 6;
  int b = blk >> 5;
  int s0 = (blk & 31) * 16;

  // stage tar_wt[b] (16 KB) + tar_mask[b]; track block maxabs(tw)
  const float4* twg = (const float4*)(tar_wt + (size_t)b * Tn * 8);
  float mloc = 0.0f;
#pragma unroll
  for (int k = 0; k < 4; ++k) {
    int idx = k * 256 + tid;  // float4 index; t=idx>>1, half=idx&1
    float4 vv = twg[idx];
    int t = idx >> 1, hf = idx & 1;
    *(float4*)&tw_lds[t * 12 + hf * 4] = vv;
    mloc = fmaxf(mloc, fmaxf(fmaxf(fabsf(vv.x), fabsf(vv.y)),
                             fmaxf(fabsf(vv.z), fabsf(vv.w))));
  }
  for (int k = tid; k < Tn; k += 256) tm_lds[k] = tar_mask[b * Tn + k];
#pragma unroll
  for (int off = 32; off; off >>= 1)
    mloc = fmaxf(mloc, __shfl_xor(mloc, off, 64));
  if (lane == 0) mred[wid] = mloc;
  __syncthreads();
  float M = fmaxf(fmaxf(mred[0], mred[1]), fmaxf(mred[2], mred[3]));

  int r = lane & 7, h = (lane >> 3) & 1, sl4 = lane >> 4;
  int s_local = wid * 4 + sl4;
  int s = s0 + s_local;

  float g_r = (r & 4) ? ((r & 2) ? ((r & 1) ? g[7] : g[6])
                                 : ((r & 1) ? g[5] : g[4]))
                      : ((r & 2) ? ((r & 1) ? g[3] : g[2])
                                 : ((r & 1) ? g[1] : g[0]));
  float sw = src_wt[((size_t)(b * Sn + s)) * 8 + r];
  float sm = src_mask[b * Sn + s];
  float a = g_r * sw;
  // sc2 = L2E*(score - m'),  score = a*tw + (1 - sm*tm)*NEG,
  // m' = |a|*M + (1-sm)*NEG  =>  sc2 = A2*tw + Bm*tm + C2, always <= 0.
  float A2 = a * L2E;
  float Bm = sm * (-NEG_BIG) * L2E;
  float C2 = L2E * (sm * NEG_BIG - fabsf(a) * M);

  float ps = 0.0f, wsum = 0.0f;
  int t0 = h * 256;
#pragma unroll 8
  for (int t = t0; t < t0 + 256; ++t) {
    float tw = tw_lds[t * 12 + r];
    float tm = tm_lds[t];
    float sc = fmaf(A2, tw, fmaf(Bm, tm, C2));
    float p = __builtin_amdgcn_exp2f(sc);
    ps += p;
    wsum = fmaf(p, tw, wsum);
  }
  // merge the two t-halves (same m' => plain adds)
  ps += __shfl_xor(ps, 8, 64);
  wsum += __shfl_xor(wsum, 8, 64);
  if (h == 0) cacc_lds[s_local * 8 + r] = wsum / ps;
  __syncthreads();

  // epilogue: wave writes 4 s-rows; w in registers; coalesced float4 stores
#pragma unroll
  for (int i = 0; i < 4; ++i) {
    int srow = wid * 4 + i;
    float4 c0 = *(const float4*)&cacc_lds[srow * 8];
    float4 c1 = *(const float4*)&cacc_lds[srow * 8 + 4];
    float cc[8] = {c0.x, c0.y, c0.z, c0.w, c1.x, c1.y, c1.z, c1.w};
    float4 o0 = {0, 0, 0, 0}, o1 = {0, 0, 0, 0};
#pragma unroll
    for (int rr = 0; rr < 8; ++rr) {
      o0.x = fmaf(cc[rr], wa[rr].x, o0.x);
      o0.y = fmaf(cc[rr], wa[rr].y, o0.y);
      o0.z = fmaf(cc[rr], wa[rr].z, o0.z);
      o0.w = fmaf(cc[rr], wa[rr].w, o0.w);
      o1.x = fmaf(cc[rr], wb[rr].x, o1.x);
      o1.y = fmaf(cc[rr], wb[rr].y, o1.y);
      o1.z = fmaf(cc[rr], wb[rr].z, o1.z);
      o1.w = fmaf(cc[rr], wb[rr].w, o1.w);
    }
    float4* dst = (float4*)(out + (size_t)(b * Sn + s0 + srow) * Dn);
    dst[lane] = o0;
    dst[64 + lane] = o1;
  }
}

// ---------------------------------------------------------------------------
// Cooperative single kernel: phase1 -> grid.sync -> phase2.
__global__ __launch_bounds__(256) void mulrel_coop(
    const float* __restrict__ src_emb, const float* __restrict__ tar_emb,
    const float* __restrict__ src_mask, const float* __restrict__ tar_mask,
    const float* __restrict__ w, float* __restrict__ src_wt,
    float* __restrict__ tar_wt, float* __restrict__ out) {
  __shared__ __align__(16) float tw_lds[Tn * 12];  // 24 KB
  __shared__ float tm_lds[Tn];
  __shared__ __align__(16) float cacc_lds[16 * 8];
  __shared__ float mred[4];

  int lane = threadIdx.x & 63;
  float4 wa[8], wb[8];
  float g[8];
  load_norm_w(w, lane, wa, wb, g);

  phase1(blockIdx.x, threadIdx.x, src_emb, tar_emb, wa, wb, src_wt, tar_wt);
  cg::this_grid().sync();
  phase2(blockIdx.x, threadIdx.x, src_wt, tar_wt, src_mask, tar_mask, wa, wb,
         g, out, tw_lds, tm_lds, cacc_lds, mred);
}

// Fallback path (identical math, two launches) in case cooperative launch
// is rejected at capture time.
__global__ __launch_bounds__(256) void k_phase1(
    const float* __restrict__ src_emb, const float* __restrict__ tar_emb,
    const float* __restrict__ w, float* __restrict__ src_wt,
    float* __restrict__ tar_wt) {
  int lane = threadIdx.x & 63;
  float4 wa[8], wb[8];
  float g[8];
  load_norm_w(w, lane, wa, wb, g);
  phase1(blockIdx.x, threadIdx.x, src_emb, tar_emb, wa, wb, src_wt, tar_wt);
}

__global__ __launch_bounds__(256) void k_phase2(
    const float* __restrict__ src_wt, const float* __restrict__ tar_wt,
    const float* __restrict__ src_mask, const float* __restrict__ tar_mask,
    const float* __restrict__ w, float* __restrict__ out) {
  __shared__ __align__(16) float tw_lds[Tn * 12];
  __shared__ float tm_lds[Tn];
  __shared__ __align__(16) float cacc_lds[16 * 8];
  __shared__ float mred[4];
  int lane = threadIdx.x & 63;
  float4 wa[8], wb[8];
  float g[8];
  load_norm_w(w, lane, wa, wb, g);
  phase2(blockIdx.x, threadIdx.x, src_wt, tar_wt, src_mask, tar_mask, wa, wb,
         g, out, tw_lds, tm_lds, cacc_lds, mred);
}

// ---------------------------------------------------------------------------
extern "C" void kernel_launch(void* const* d_in, const int* in_sizes, int n_in,
                              void* d_out, int out_size, void* d_ws,
                              size_t ws_size, hipStream_t stream) {
  const float* src_emb = (const float*)d_in[0];   // [B,S,D]
  const float* tar_emb = (const float*)d_in[1];   // [B,T,D]
  const float* src_mask = (const float*)d_in[2];  // [B,S]
  const float* tar_mask = (const float*)d_in[3];  // [B,T]
  const float* w_in = (const float*)d_in[4];      // [R,D]
  float* out = (float*)d_out;                     // [B,S,D]

  float* ws = (float*)d_ws;
  float* src_wt = ws;            // [B*S][R] = 65536 floats
  float* tar_wt = ws + 65536;    // [B*T][R] = 65536 floats

  void* args[] = {(void*)&src_emb, (void*)&tar_emb, (void*)&src_mask,
                  (void*)&tar_mask, (void*)&w_in,   (void*)&src_wt,
                  (void*)&tar_wt,   (void*)&out};
  hipError_t err = hipLaunchCooperativeKernel(
      (void*)mulrel_coop, dim3(NBLK), dim3(256), args, 0, stream);
  if (err != hipSuccess) {
    k_phase1<<<NBLK, 256, 0, stream>>>(src_emb, tar_emb, w_in, src_wt, tar_wt);
    k_phase2<<<NBLK, 256, 0, stream>>>(src_wt, tar_wt, src_mask, tar_mask,
                                       w_in, out);
  }
}

// Round 7
// 103.063 us; speedup vs baseline: 1.5272x; 1.5272x over previous
//
#include <hip/hip_runtime.h>
#include <hip/hip_bf16.h>
#include <math.h>

// B=16, S=T=512, D=512, R=8.  All float32.
#define B 16
#define Sn 512
#define Tn 512
#define Dn 512
#define NEG_BIG (-1e10f)
#define L2E 1.4426950408889634f
#define TW_STRIDE 516  // 512 + 4 pad: row r starts at bank 4r -> conflict-free

__device__ __forceinline__ float dot4(float4 a, float4 b) {
  return a.x * b.x + a.y * b.y + a.z * b.z + a.w * b.w;
}

// Sum p[0..7] across 64 lanes with 10 shuffles. Every lane returns the
// total for r = lane&7.
__device__ __forceinline__ float fold_reduce8(const float* p, int lane) {
  bool b0 = lane & 1;
  float q[4];
#pragma unroll
  for (int j = 0; j < 4; ++j) {
    float s = b0 ? p[2 * j] : p[2 * j + 1];
    float rv = __shfl_xor(s, 1, 64);
    q[j] = (b0 ? p[2 * j + 1] : p[2 * j]) + rv;
  }
  bool b1 = lane & 2;
  float u[2];
#pragma unroll
  for (int j = 0; j < 2; ++j) {
    float s = b1 ? q[2 * j] : q[2 * j + 1];
    float rv = __shfl_xor(s, 2, 64);
    u[j] = (b1 ? q[2 * j + 1] : q[2 * j]) + rv;
  }
  bool b2 = lane & 4;
  float s = b2 ? u[0] : u[1];
  float rv = __shfl_xor(s, 4, 64);
  float v = (b2 ? u[1] : u[0]) + rv;
  v += __shfl_xor(v, 8, 64);
  v += __shfl_xor(v, 16, 64);
  v += __shfl_xor(v, 32, 64);
  return v;
}

// w[8][512] -> registers (lane's d4-slices: lane and 64+lane), row-normalized;
// g[r] = ||w_r||^2 post-normalize (kept for exactness vs reference).
__device__ __forceinline__ void load_norm_w(const float* __restrict__ w,
                                            int lane, float4* wa, float4* wb,
                                            float* g) {
  const float4* wg = (const float4*)w;
  float ss[8];
#pragma unroll
  for (int r = 0; r < 8; ++r) {
    wa[r] = wg[r * 128 + lane];
    wb[r] = wg[r * 128 + 64 + lane];
    ss[r] = dot4(wa[r], wa[r]) + dot4(wb[r], wb[r]);
  }
#pragma unroll
  for (int off = 32; off; off >>= 1) {
#pragma unroll
    for (int r = 0; r < 8; ++r) ss[r] += __shfl_xor(ss[r], off, 64);
  }
#pragma unroll
  for (int r = 0; r < 8; ++r) {
    float iv = 1.0f / fmaxf(sqrtf(ss[r]), 1e-12f);
    wa[r].x *= iv; wa[r].y *= iv; wa[r].z *= iv; wa[r].w *= iv;
    wb[r].x *= iv; wb[r].y *= iv; wb[r].z *= iv; wb[r].w *= iv;
    g[r] = ss[r] * iv * iv;
  }
}

// ---------------------------------------------------------------------------
// Kernel 1: wt[row][r] = <emb[row,:], w_norm[r,:]>, layout [b*512+n][8].
// 2048 blocks x 256; wave handles 2 rows (max TLP for the 33.5 MB stream).
__global__ __launch_bounds__(256) void k_phase1(
    const float* __restrict__ src_emb, const float* __restrict__ tar_emb,
    const float* __restrict__ w, float* __restrict__ src_wt,
    float* __restrict__ tar_wt) {
  int lane = threadIdx.x & 63, wid = threadIdx.x >> 6;
  float4 wa[8], wb[8];
  float g[8];
  load_norm_w(w, lane, wa, wb, g);

  int row0 = blockIdx.x * 8 + wid * 2;
  bool is_src = row0 < B * Sn;
  const float* emb = is_src ? src_emb : tar_emb;
  float* wt = is_src ? src_wt : tar_wt;
  int rb = is_src ? row0 : row0 - B * Sn;

  const float4* e0 = (const float4*)(emb + (size_t)rb * Dn);
  const float4* e1 = (const float4*)(emb + (size_t)(rb + 1) * Dn);
  float4 x0a = e0[lane], x0b = e0[64 + lane];
  float4 x1a = e1[lane], x1b = e1[64 + lane];
  float p0[8], p1[8];
#pragma unroll
  for (int r = 0; r < 8; ++r) {
    p0[r] = dot4(x0a, wa[r]) + dot4(x0b, wb[r]);
    p1[r] = dot4(x1a, wa[r]) + dot4(x1b, wb[r]);
  }
  float v0 = fold_reduce8(p0, lane);  // independent chains -> ILP
  float v1 = fold_reduce8(p1, lane);
  if (lane < 8) wt[(size_t)rb * 8 + lane] = v0;
  else if (lane < 16) wt[(size_t)(rb + 1) * 8 + (lane & 7)] = v1;
}

// ---------------------------------------------------------------------------
// Kernel 2: fused softmax + output for 8 s-rows per block (1024 blocks).
// Lane owns one (s = s0 + lane>>3, r = lane&7); wave wid handles t-quarter
// [wid*128, wid*128+128).  tw staged transposed [r][t] (pad 4 -> bank-spread),
// read as float4-over-t (8 distinct addrs/wave = near-free); tm broadcast
// float4.  Cross-wave partial (ps,wsum) reduce via LDS.  Softmax uses the
// analytic shift bound m' = |a|*maxabs(tw) + (1-sm)*NEG (shift-invariant,
// exact same softmax value; never overflows, all-masked rows safe).
__global__ __launch_bounds__(256, 4) void k_phase2(
    const float* __restrict__ src_wt, const float* __restrict__ tar_wt,
    const float* __restrict__ src_mask, const float* __restrict__ tar_mask,
    const float* __restrict__ w, float* __restrict__ out) {
  __shared__ float tw_lds[8 * TW_STRIDE];          // 16.1 KB, transposed [r][t]
  __shared__ __align__(16) float tm_lds[Tn];       // 2 KB
  __shared__ float red_ps[4][64], red_ws[4][64];   // 2 KB
  __shared__ float cacc[64];
  __shared__ float mred[4];

  int tid = threadIdx.x, lane = tid & 63, wid = tid >> 6;
  int b = blockIdx.x >> 6;        // 64 blocks per b
  int s0 = (blockIdx.x & 63) * 8;

  float4 wa[8], wb[8];
  float g[8];
  load_norm_w(w, lane, wa, wb, g);

  // stage tar_wt[b] (16 KB) transposed into [r][t]; track block maxabs(tw)
  const float4* twg = (const float4*)(tar_wt + (size_t)b * Tn * 8);
  float mloc = 0.0f;
#pragma unroll
  for (int k = 0; k < 4; ++k) {
    int idx = k * 256 + tid;  // float4 index; t = idx>>1, r-half = idx&1
    float4 vv = twg[idx];
    int t = idx >> 1, h = idx & 1;
    tw_lds[(4 * h + 0) * TW_STRIDE + t] = vv.x;
    tw_lds[(4 * h + 1) * TW_STRIDE + t] = vv.y;
    tw_lds[(4 * h + 2) * TW_STRIDE + t] = vv.z;
    tw_lds[(4 * h + 3) * TW_STRIDE + t] = vv.w;
    mloc = fmaxf(mloc, fmaxf(fmaxf(fabsf(vv.x), fabsf(vv.y)),
                             fmaxf(fabsf(vv.z), fabsf(vv.w))));
  }
  if (tid < 128)
    *(float4*)&tm_lds[tid * 4] = ((const float4*)(tar_mask + b * Tn))[tid];
#pragma unroll
  for (int off = 32; off; off >>= 1)
    mloc = fmaxf(mloc, __shfl_xor(mloc, off, 64));
  if (lane == 0) mred[wid] = mloc;
  __syncthreads();
  float M = fmaxf(fmaxf(mred[0], mred[1]), fmaxf(mred[2], mred[3]));

  int r = lane & 7, sl = lane >> 3;
  int s = s0 + sl;

  float g_r = (r & 4) ? ((r & 2) ? ((r & 1) ? g[7] : g[6])
                                 : ((r & 1) ? g[5] : g[4]))
                      : ((r & 2) ? ((r & 1) ? g[3] : g[2])
                                 : ((r & 1) ? g[1] : g[0]));
  float sw = src_wt[((size_t)(b * Sn + s0)) * 8 + lane];  // == (b*S+s)*8+r
  float sm = src_mask[b * Sn + s];
  float a = g_r * sw;
  // sc2 = L2E*(score - m'); score = a*tw + (1 - sm*tm)*NEG;
  // m' = |a|*M + (1-sm)*NEG  =>  sc2 = A2*tw + Bm*tm + C2, always <= 0.
  float A2 = a * L2E;
  float Bm = sm * (-NEG_BIG) * L2E;
  float C2 = L2E * (sm * NEG_BIG - fabsf(a) * M);

  float ps = 0.0f, wsum = 0.0f;
  const float* twr = &tw_lds[r * TW_STRIDE + wid * 128];
  const float* tmr = &tm_lds[wid * 128];
#pragma unroll 8
  for (int i = 0; i < 32; ++i) {
    float4 tw4 = *(const float4*)&twr[i * 4];
    float4 tm4 = *(const float4*)&tmr[i * 4];
    float sc, p;
    sc = fmaf(A2, tw4.x, fmaf(Bm, tm4.x, C2));
    p = __builtin_amdgcn_exp2f(sc); ps += p; wsum = fmaf(p, tw4.x, wsum);
    sc = fmaf(A2, tw4.y, fmaf(Bm, tm4.y, C2));
    p = __builtin_amdgcn_exp2f(sc); ps += p; wsum = fmaf(p, tw4.y, wsum);
    sc = fmaf(A2, tw4.z, fmaf(Bm, tm4.z, C2));
    p = __builtin_amdgcn_exp2f(sc); ps += p; wsum = fmaf(p, tw4.z, wsum);
    sc = fmaf(A2, tw4.w, fmaf(Bm, tm4.w, C2));
    p = __builtin_amdgcn_exp2f(sc); ps += p; wsum = fmaf(p, tw4.w, wsum);
  }
  red_ps[wid][lane] = ps;
  red_ws[wid][lane] = wsum;
  __syncthreads();
  if (wid == 0) {
    float pst = red_ps[0][lane] + red_ps[1][lane] + red_ps[2][lane] +
                red_ps[3][lane];
    float wst = red_ws[0][lane] + red_ws[1][lane] + red_ws[2][lane] +
                red_ws[3][lane];
    cacc[lane] = wst / pst;  // c for (s = s0 + lane>>3, r = lane&7)
  }
  __syncthreads();

  // epilogue: wave wid writes s-rows {2*wid, 2*wid+1}; w in registers.
#pragma unroll
  for (int i = 0; i < 2; ++i) {
    int srow = wid * 2 + i;
    float cc[8];
#pragma unroll
    for (int rr = 0; rr < 8; ++rr) cc[rr] = cacc[srow * 8 + rr];  // broadcast
    float4 o0 = {0, 0, 0, 0}, o1 = {0, 0, 0, 0};
#pragma unroll
    for (int rr = 0; rr < 8; ++rr) {
      o0.x = fmaf(cc[rr], wa[rr].x, o0.x);
      o0.y = fmaf(cc[rr], wa[rr].y, o0.y);
      o0.z = fmaf(cc[rr], wa[rr].z, o0.z);
      o0.w = fmaf(cc[rr], wa[rr].w, o0.w);
      o1.x = fmaf(cc[rr], wb[rr].x, o1.x);
      o1.y = fmaf(cc[rr], wb[rr].y, o1.y);
      o1.z = fmaf(cc[rr], wb[rr].z, o1.z);
      o1.w = fmaf(cc[rr], wb[rr].w, o1.w);
    }
    float4* dst = (float4*)(out + (size_t)(b * Sn + s0 + srow) * Dn);
    dst[lane] = o0;
    dst[64 + lane] = o1;
  }
}

// ---------------------------------------------------------------------------
extern "C" void kernel_launch(void* const* d_in, const int* in_sizes, int n_in,
                              void* d_out, int out_size, void* d_ws,
                              size_t ws_size, hipStream_t stream) {
  const float* src_emb = (const float*)d_in[0];   // [B,S,D]
  const float* tar_emb = (const float*)d_in[1];   // [B,T,D]
  const float* src_mask = (const float*)d_in[2];  // [B,S]
  const float* tar_mask = (const float*)d_in[3];  // [B,T]
  const float* w_in = (const float*)d_in[4];      // [R,D]
  float* out = (float*)d_out;                     // [B,S,D]

  float* ws = (float*)d_ws;
  float* src_wt = ws;            // [B*S][8] = 65536 floats
  float* tar_wt = ws + 65536;    // [B*T][8] = 65536 floats

  k_phase1<<<(B * (Sn + Tn)) / 8, 256, 0, stream>>>(src_emb, tar_emb, w_in,
                                                    src_wt, tar_wt);
  k_phase2<<<B * (Sn / 8), 256, 0, stream>>>(src_wt, tar_wt, src_mask,
                                             tar_mask, w_in, out);
}